// Round 6
// baseline (198.064 us; speedup 1.0000x reference)
//
#include <hip/hip_runtime.h>
#include <hip/hip_bf16.h>
#include <math.h>

// DotProductAttention: B=16, Q=2048, K=2048, D=128, fp32 in/out.
// Query-axis masking: rows q >= valid_lens[b] -> uniform softmax -> mean(V)
// (combine writes those rows exactly from fp32 V column sums).
//
// Round 6:
//  - flash: 64 q-rows per wave (2 rowsets A/B share every K and V fragment
//    read) -> LDS reads per q halved; BQ=256 -> 512 active blocks = exact
//    2-blocks/CU residency. 32x32x16 MFMA S^T slot-permutation layout
//    (verified R5): pi = swap bits 2<->3; S^T C-regs ARE the PV A-fragment.
//  - prep: LDS-free; V-transpose granules assembled in-register (8 strided
//    coalesced loads -> one 16B swizzled store); K as 16B granules too.
//  - combine: f16x8 16B partial loads, float4 stores.
//
// ws: [0,8K) sumV | Kh 8M (swizzled granules) | Vt 8M (128-key tiles,
//     swizzled) | Po f16 SEG planes | Lb f32. SEG=8 needs 84.94MB (proven R5).

#define Bn 16
#define Qn 2048
#define Kn 2048
#define Dn 128
#define SCALE 0.08838834764831845f  // 1/sqrt(128)

typedef _Float16 f16;
typedef _Float16 f16x4_t __attribute__((ext_vector_type(4)));
typedef _Float16 f16x8_t __attribute__((ext_vector_type(8)));
typedef float f32x16_t __attribute__((ext_vector_type(16)));

typedef __attribute__((address_space(1))) const unsigned int glb_u32;
typedef __attribute__((address_space(3))) unsigned int lds_u32;

__device__ __forceinline__ void g2l16(const void* g, void* l) {
  __builtin_amdgcn_global_load_lds((glb_u32*)g, (lds_u32*)l, 16, 0, 0);
}

// ---------------- prep: K->f16 swizzled granules, V->Vt granules, colsum(V)
// grid (32, 4, 16) block (32,8).  Layouts (identical to R5):
// Kh key-row k (256B): granule G=d>>3 stored at slot (G&8)|((G&7)^(k&7)).
// Vt tile [b][kb][d][kk] (32KB): granule G=kk>>3 at slot (G&8)|((G&7)^(d&7)).

__global__ void __launch_bounds__(256) prep_kernel(
    const float* __restrict__ Kg, const float* __restrict__ Vg,
    f16* __restrict__ Kh, f16* __restrict__ Vt, float* __restrict__ sv) {
  __shared__ float ps[8][32];
  const int b = blockIdx.z;
  const int x = threadIdx.x, y = threadIdx.y;

  // K: 16 key-rows per block, one granule (8 d) per thread, 16B store
  {
    const int lb = (b * 4 + blockIdx.y) * 32 + blockIdx.x;  // 0..2047
    const int t = y * 32 + x;
    const size_t key = (size_t)lb * 16 + (t >> 4);  // global (b*2048+k)
    const int G = t & 15;
    const float* kp = Kg + (key << 7) + G * 8;
    float4 f0 = *(const float4*)kp;
    float4 f1 = *(const float4*)(kp + 4);
    f16x8_t o;
    o[0] = (f16)f0.x; o[1] = (f16)f0.y; o[2] = (f16)f0.z; o[3] = (f16)f0.w;
    o[4] = (f16)f1.x; o[5] = (f16)f1.y; o[6] = (f16)f1.z; o[7] = (f16)f1.w;
    const int gs = (G & 8) | ((G & 7) ^ ((int)key & 7));
    *(f16x8_t*)(Kh + (key << 7) + (gs << 3)) = o;
  }

  // V: 64 keys x 32 d per block; thread owns one Vt granule in-register
  const int k0 = blockIdx.x * 64, d0 = blockIdx.y * 32;
  const int d = d0 + x;
  const float* vp = Vg + ((size_t)b * Kn + k0 + y * 8) * Dn + d;
  float s = 0.f;
  f16x8_t gr;
#pragma unroll
  for (int j = 0; j < 8; j++) {
    float v = vp[(size_t)j * Dn];
    s += v;
    gr[j] = (f16)v;
  }
  {
    const int kb = k0 >> 7;
    const int G = ((k0 & 64) >> 3) + y;  // kk granule index 0..15
    const int gs = (G & 8) | ((G & 7) ^ (d & 7));
    *(f16x8_t*)(Vt + (((size_t)(b * (Kn / 128) + kb) * 128 + d) << 7) + (gs << 3)) = gr;
  }

  // column sums for the masked fast path
  ps[y][x] = s;
  __syncthreads();
  if (y == 0) {
    float tot = 0.f;
#pragma unroll
    for (int j = 0; j < 8; j++) tot += ps[j][x];
    atomicAdd(&sv[b * Dn + d0 + x], tot);
  }
}

// valid_lens may be stored as int32 or int64. Sniff: odd words all zero -> 64.
__device__ __forceinline__ int load_vl(const int* __restrict__ vlp, int b) {
  bool is64 = true;
#pragma unroll
  for (int i = 1; i < 16; i += 2) is64 = is64 && (vlp[i] == 0);
  return is64 ? vlp[2 * b] : vlp[b];
}

// ---------------- flash: 32x32 MFMA, 64 q/wave, staged 128-key tiles --------
// grid (8, 16, S) block 256

template <int S>
__global__ void __launch_bounds__(256, 2) flash_kernel(
    const float* __restrict__ Qg, const f16* __restrict__ Kh,
    const f16* __restrict__ Vt, const int* __restrict__ vlp,
    f16* __restrict__ Po, float* __restrict__ Lb) {
  const int b = blockIdx.y;
  const int seg = blockIdx.z;
  const int qt = (blockIdx.x * 3 + seg * 5) & 7;  // scatter active tiles
  const int q0 = qt * 256;
  const int vl = load_vl(vlp, b);
  if (q0 >= vl) return;  // uniform per block, before any barrier

  __shared__ __align__(16) f16 Ks[128 * 128];  // 32 KB
  __shared__ __align__(16) f16 Vs[128 * 128];  // 32 KB

  const int tid = threadIdx.x;
  const int wave = tid >> 6, lane = tid & 63;
  const int H = lane >> 5, l5 = lane & 31;
  const int qbA = q0 + wave * 64, qbB = qbA + 32;
  const bool act = qbA < vl;  // wave-level early skip of compute
  const int qA = qbA + l5, qB = qbB + l5;
  const float scA = (qA >= vl) ? 0.f : SCALE;  // masked row: p=1 -> uniform
  const float scB = (qB >= vl) ? 0.f : SCALE;

  // pi = swap bits 2<->3: A-row slot l5 holds physical key pi(l5)  [R5-verified]
  const int krow = (l5 & 0x13) | ((l5 & 4) << 1) | ((l5 & 8) >> 1);
  const int krow7 = krow & 7;

  // Q fragments (B-operand of S^T): lane = q-col, k-els d = 16s+8H+j
  f16x8_t qfA[8], qfB[8];
  if (act) {
    const float* qpa = Qg + ((size_t)b * Qn + qA) * Dn + 8 * H;
    const float* qpb = Qg + ((size_t)b * Qn + qB) * Dn + 8 * H;
#pragma unroll
    for (int s = 0; s < 8; s++) {
      float4 a0 = *(const float4*)(qpa + 16 * s);
      float4 a1 = *(const float4*)(qpa + 16 * s + 4);
      float4 b0 = *(const float4*)(qpb + 16 * s);
      float4 b1 = *(const float4*)(qpb + 16 * s + 4);
      f16x8_t fa, fb;
      fa[0] = (f16)a0.x; fa[1] = (f16)a0.y; fa[2] = (f16)a0.z; fa[3] = (f16)a0.w;
      fa[4] = (f16)a1.x; fa[5] = (f16)a1.y; fa[6] = (f16)a1.z; fa[7] = (f16)a1.w;
      fb[0] = (f16)b0.x; fb[1] = (f16)b0.y; fb[2] = (f16)b0.z; fb[3] = (f16)b0.w;
      fb[4] = (f16)b1.x; fb[5] = (f16)b1.y; fb[6] = (f16)b1.z; fb[7] = (f16)b1.w;
      qfA[s] = fa; qfB[s] = fb;
    }
  }

  f32x16_t OA[4], OB[4];
#pragma unroll
  for (int i = 0; i < 4; i++) {
    OA[i] = (f32x16_t)(0.f);
    OB[i] = (f32x16_t)(0.f);
  }
  float lA = 0.f, lB = 0.f;

  const char* KgT = (const char*)(Kh + (((size_t)b * Kn + (size_t)seg * (Kn / S)) << 7));
  const char* VgT = (const char*)(Vt + (((size_t)(b * (Kn / 128) + seg * (Kn / S) / 128)) << 14));

  for (int it = 0; it < (Kn / S) / 128; it++) {
    __syncthreads();  // protect LDS from previous iter's readers
    // stage 64 KB: 16 x 1KB chunks per wave (8 K + 8 V), width-16 DMA
    const char* kg = KgT + (size_t)it * 32768 + (size_t)(wave * 8) * 1024 + lane * 16;
    const char* vg = VgT + (size_t)it * 32768 + (size_t)(wave * 8) * 1024 + lane * 16;
    f16* kl = Ks + wave * 8 * 512;
    f16* vli = Vs + wave * 8 * 512;
#pragma unroll
    for (int i = 0; i < 8; i++) {
      g2l16(kg + i * 1024, kl + i * 512);
      g2l16(vg + i * 1024, vli + i * 512);
    }
    __syncthreads();

    if (act) {
#pragma unroll
      for (int sub = 0; sub < 4; sub++) {
        // S^T = K.Q^T over keys sub*32..+31; kf shared by both rowsets
        f32x16_t TA = (f32x16_t)(0.f), TB = (f32x16_t)(0.f);
        const f16* krp = Ks + ((sub * 32 + krow) << 7);
#pragma unroll
        for (int s = 0; s < 8; s++) {
          const int G = 2 * s + H;
          const int gs = (G & 8) | ((G & 7) ^ krow7);
          f16x8_t kf = *(const f16x8_t*)(krp + (gs << 3));
          TA = __builtin_amdgcn_mfma_f32_32x32x16_f16(kf, qfA[s], TA, 0, 0, 0);
          TB = __builtin_amdgcn_mfma_f32_32x32x16_f16(kf, qfB[s], TB, 0, 0, 0);
        }

        // p = exp(s); C-regs are the PV A-fragment (key 16(r>>3)+8H+(r&7))
        f16x8_t pA0, pA1, pB0, pB1;
        float la = 0.f, lb2 = 0.f;
#pragma unroll
        for (int r = 0; r < 8; r++) {
          float a = __expf(TA[r] * scA);
          float bq = __expf(TB[r] * scB);
          la += a; lb2 += bq;
          pA0[r] = (f16)a; pB0[r] = (f16)bq;
        }
#pragma unroll
        for (int r = 8; r < 16; r++) {
          float a = __expf(TA[r] * scA);
          float bq = __expf(TB[r] * scB);
          la += a; lb2 += bq;
          pA1[r - 8] = (f16)a; pB1[r - 8] = (f16)bq;
        }
        lA += la; lB += lb2;

        // O += P.V ; vf shared by both rowsets
#pragma unroll
        for (int dt = 0; dt < 4; dt++) {
          const f16* vrp = Vs + ((dt * 32 + l5) << 7);
          const int G0 = sub * 4 + H, G1 = sub * 4 + 2 + H;
          const int gs0 = (G0 & 8) | ((G0 & 7) ^ (l5 & 7));
          const int gs1 = (G1 & 8) | ((G1 & 7) ^ (l5 & 7));
          f16x8_t vf0 = *(const f16x8_t*)(vrp + (gs0 << 3));
          f16x8_t vf1 = *(const f16x8_t*)(vrp + (gs1 << 3));
          OA[dt] = __builtin_amdgcn_mfma_f32_32x32x16_f16(pA0, vf0, OA[dt], 0, 0, 0);
          OA[dt] = __builtin_amdgcn_mfma_f32_32x32x16_f16(pA1, vf1, OA[dt], 0, 0, 0);
          OB[dt] = __builtin_amdgcn_mfma_f32_32x32x16_f16(pB0, vf0, OB[dt], 0, 0, 0);
          OB[dt] = __builtin_amdgcn_mfma_f32_32x32x16_f16(pB1, vf1, OB[dt], 0, 0, 0);
        }
      }
    }
  }

  if (!act) return;

  // epilogue: unnormalized partials
  lA += __shfl_xor(lA, 32);
  lB += __shfl_xor(lB, 32);
  if (lane < 32) {
    Lb[(size_t)(seg * Bn + b) * Qn + qbA + l5] = lA;
    Lb[(size_t)(seg * Bn + b) * Qn + qbB + l5] = lB;
  }

  f16* poA = Po + ((size_t)(seg * Bn + b) * Qn + qbA) * Dn;
  f16* poB = Po + ((size_t)(seg * Bn + b) * Qn + qbB) * Dn;
#pragma unroll
  for (int dt = 0; dt < 4; dt++) {
#pragma unroll
    for (int r = 0; r < 16; r++) {
      const int qrow = (r & 3) + 8 * (r >> 2) + 4 * H;  // PV C-layout row
      poA[(size_t)qrow * Dn + dt * 32 + l5] = (f16)OA[dt][r];
      poB[(size_t)qrow * Dn + dt * 32 + l5] = (f16)OB[dt][r];
    }
  }
}

// ---------------- combine: out = sum_s O_s / sum_s l_s; masked rows = mean(V)
// grid (32, 16) block 256; 64 q-rows per block, 8 d per thread.

template <int S>
__global__ void __launch_bounds__(256) combine_kernel(
    const f16* __restrict__ Po, const float* __restrict__ Lb,
    const float* __restrict__ sv, const int* __restrict__ vlp,
    float* __restrict__ Out) {
  const int b = blockIdx.y, q0 = blockIdx.x * 64;
  const int vl = load_vl(vlp, b);
  const int tid = threadIdx.x;

  __shared__ float linv[64];
  if (tid < 64) {
    float s = 0.f;
#pragma unroll
    for (int sg = 0; sg < S; sg++) s += Lb[(size_t)(sg * Bn + b) * Qn + q0 + tid];
    linv[tid] = 1.0f / s;
  }
  __syncthreads();

  const int row16 = tid >> 4;      // 0..15
  const int d8 = (tid & 15) * 8;   // 0..120
  const float invK = 1.0f / (float)Kn;
  float mv[8];
#pragma unroll
  for (int j = 0; j < 8; j++) mv[j] = sv[b * Dn + d8 + j] * invK;

#pragma unroll
  for (int pass = 0; pass < 4; pass++) {
    const int row = pass * 16 + row16;
    const int q = q0 + row;
    float acc[8];
    if (q >= vl) {
#pragma unroll
      for (int j = 0; j < 8; j++) acc[j] = mv[j];  // fp32-exact uniform result
    } else {
#pragma unroll
      for (int j = 0; j < 8; j++) acc[j] = 0.f;
#pragma unroll
      for (int sg = 0; sg < S; sg++) {
        f16x8_t v = *(const f16x8_t*)(Po + ((size_t)(sg * Bn + b) * Qn + q) * Dn + d8);
#pragma unroll
        for (int j = 0; j < 8; j++) acc[j] += (float)v[j];
      }
      const float li = linv[row];
#pragma unroll
      for (int j = 0; j < 8; j++) acc[j] *= li;
    }
    float4 o0 = make_float4(acc[0], acc[1], acc[2], acc[3]);
    float4 o1 = make_float4(acc[4], acc[5], acc[6], acc[7]);
    float* op = Out + ((size_t)b * Qn + q) * Dn + d8;
    *(float4*)op = o0;
    *(float4*)(op + 4) = o1;
  }
}

// ---------------- launch ----------------

extern "C" void kernel_launch(void* const* d_in, const int* in_sizes, int n_in,
                              void* d_out, int out_size, void* d_ws, size_t ws_size,
                              hipStream_t stream) {
  const float* Qg = (const float*)d_in[0];
  const float* Kg = (const float*)d_in[1];
  const float* Vg = (const float*)d_in[2];
  const int* vl = (const int*)d_in[3];
  float* Out = (float*)d_out;

  char* ws = (char*)d_ws;
  float* sumV = (float*)ws;                                // 8 KB
  f16* Kh = (f16*)(ws + 8192);                             // 8 MB
  f16* Vt = (f16*)(ws + 8192 + (size_t)Bn * Kn * Dn * 2);  // 8 MB
  const size_t base = 8192 + 2 * (size_t)Bn * Kn * Dn * 2;
  f16* Po = (f16*)(ws + base);

  const size_t po8 = (size_t)8 * Bn * Qn * Dn * 2;  // 67.1 MB
  const size_t lb8 = (size_t)8 * Bn * Qn * 4;       // 1.0 MB
  const size_t po4 = (size_t)4 * Bn * Qn * Dn * 2;  // 33.6 MB
  const size_t need8 = base + po8 + lb8;            // 84.94 MB (proven fits R5)

  hipMemsetAsync(sumV, 0, Bn * Dn * sizeof(float), stream);
  prep_kernel<<<dim3(32, 4, Bn), dim3(32, 8), 0, stream>>>(Kg, Vg, Kh, Vt, sumV);

  if (ws_size >= need8) {
    float* Lb = (float*)(ws + base + po8);
    flash_kernel<8><<<dim3(8, Bn, 8), 256, 0, stream>>>(Qg, Kh, Vt, vl, Po, Lb);
    combine_kernel<8><<<dim3(Qn / 64, Bn), 256, 0, stream>>>(Po, Lb, sumV, vl, Out);
  } else {
    float* Lb = (float*)(ws + base + po4);
    flash_kernel<4><<<dim3(8, Bn, 4), 256, 0, stream>>>(Qg, Kh, Vt, vl, Po, Lb);
    combine_kernel<4><<<dim3(Qn / 64, Bn), 256, 0, stream>>>(Po, Lb, sumV, vl, Out);
  }
}